// Round 3
// baseline (204.404 us; speedup 1.0000x reference)
//
#include <hip/hip_runtime.h>
#include <hip/hip_fp16.h>
#include <hip/hip_cooperative_groups.h>

// SilkNNUE R14 — shfl-free int8 gather + single cooperative main kernel.
//   R13 post-mortem: gather bytes/requests DON'T limit (R12 occupancy-null,
//   R13 byte-halving-null). R13 was DS-pipe-bound (29 DS-ops/row: butterfly
//   24 + idx 4 + write 1 at ~9cyc => ~55us). R12 was TA-bound (128 CL/row).
//   Launch overhead: R13's +2 dispatches (+memset) cost ~47us of bench.
// Fix:
//   * Gather: lane=(rr,p): rr=lane>>3 owns a training row, p=lane&7 owns a
//     16B packet of the 128B int8 row. 32 features accumulate serially into
//     8 u32 accumulators (16-bit slots, max 32*255=8160, exact). NO shfl.
//     DS per row-equiv: 4 idx reads + 0.25 writes (was 29). CL same as R13.
//   * Chain: absmax_partial (plain, per-block slots, no atomics/memset) ->
//     nnue_all (cooperative): reduce slots + quantize + W2h/W3h, grid.sync,
//     then NNUE. 2 launches total (same count as best-known R12).
//   * MFMA dense chain + swizzled hT layout unchanged (R9/R11-verified).

namespace cg = cooperative_groups;

typedef _Float16 h2v_t  __attribute__((ext_vector_type(2)));
typedef _Float16 half8  __attribute__((ext_vector_type(8)));
typedef float    f32x4  __attribute__((ext_vector_type(4)));

constexpr int RPB = 64;   // rows per chunk

// ---- per-block absmax partials (no atomics, no init needed) ---------------
__global__ __launch_bounds__(256) void absmax_partial(
    const float4* __restrict__ emb4, float* __restrict__ slots, int n4)
{
    __shared__ float red[4];
    const int i = blockIdx.x * blockDim.x + threadIdx.x;
    float m = 0.f;
    if (i < n4) {
        float4 v = emb4[i];
        m = fmaxf(fmaxf(fabsf(v.x), fabsf(v.y)), fmaxf(fabsf(v.z), fabsf(v.w)));
    }
    #pragma unroll
    for (int s = 1; s < 64; s <<= 1)
        m = fmaxf(m, __shfl_xor(m, s));
    if ((threadIdx.x & 63) == 0) red[threadIdx.x >> 6] = m;
    __syncthreads();
    if (threadIdx.x == 0)
        slots[blockIdx.x] = fmaxf(fmaxf(red[0], red[1]), fmaxf(red[2], red[3]));
}

// ---------------- cooperative: quantize + sync + fused NNUE ----------------
__global__ __launch_bounds__(256, 4) void nnue_all(
    const int*    __restrict__ x,      // (N,32)
    const float4* __restrict__ emb4,   // (7424,128) fp32 as float4
    unsigned*     __restrict__ emb8,   // ws: (7425,128) u8 permuted (d0,d2,d1,d3)
    const float*  __restrict__ W2,
    const float*  __restrict__ W3,
    _Float16*     __restrict__ W2h,    // ws: (32,128) fp16
    _Float16*     __restrict__ W3h,    // ws: (32,64) fp16
    const float*  __restrict__ b2,
    const float*  __restrict__ b3,
    const float*  __restrict__ W4,     // (64,)
    const float*  __restrict__ slots,  // 1024 partial absmax
    float*        __restrict__ out, int n)
{
    // per-wave: hT = 16 rows x 16 uint4 (swizzled), later aliased by a2 tile
    __shared__ __align__(16) char hmem[4][4096];   // 16384 B
    // per-wave packed u16 indices: 16 rows x 32 (phase B reuses as red[])
    __shared__ __align__(16) char xmem[4][1024];   //  4096 B  (total 20480)

    const int tid  = threadIdx.x;
    const int lane = tid & 63;
    const int wave = tid >> 6;

    // ===================== phase B: scale + quantize =======================
    float amax;
    {
        float* red = (float*)&xmem[0][0];
        const float4* s4 = (const float4*)slots;     // 256 float4 = 1024 slots
        float4 v = s4[tid];
        float m = fmaxf(fmaxf(v.x, v.y), fmaxf(v.z, v.w));
        #pragma unroll
        for (int s = 1; s < 64; s <<= 1)
            m = fmaxf(m, __shfl_xor(m, s));
        if (lane == 0) red[wave] = m;
        __syncthreads();
        amax = fmaxf(fmaxf(red[0], red[1]), fmaxf(red[2], red[3]));
        amax = fmaxf(amax, 1e-20f);
        __syncthreads();    // red (xmem) dead before staging reuses it
    }
    const float qs = 127.f / amax;
    {
        const int gstep = (int)gridDim.x * 256;
        for (int i = blockIdx.x * 256 + tid; i < 7425 * 32; i += gstep) {
            unsigned w = 0x80808080u;              // zero row 7424
            if (i < 7424 * 32) {
                float4 v = emb4[i];
                int q0 = min(127, max(-127, (int)rintf(v.x * qs)));
                int q1 = min(127, max(-127, (int)rintf(v.y * qs)));
                int q2 = min(127, max(-127, (int)rintf(v.z * qs)));
                int q3 = min(127, max(-127, (int)rintf(v.w * qs)));
                // byte order (d0,d2,d1,d3): lo-mask slots = dims (4j,4j+1),
                // hi-perm slots = dims (4j+2,4j+3)
                w = (unsigned)(q0 + 128)
                  | ((unsigned)(q2 + 128) << 8)
                  | ((unsigned)(q1 + 128) << 16)
                  | ((unsigned)(q3 + 128) << 24);
            }
            emb8[i] = w;
        }
        for (int i = blockIdx.x * 256 + tid; i < 4096; i += gstep)
            W2h[i] = (_Float16)W2[i];
        for (int i = blockIdx.x * 256 + tid; i < 2048; i += gstep)
            W3h[i] = (_Float16)W3[i];
    }
    __threadfence();
    cg::this_grid().sync();

    // ===================== phase C: fused NNUE =============================
    const float sc = amax * (1.f / 127.f);
    const float cb = -4096.f * sc;                 // 32 features x 128 bias
    const int rr = lane >> 3;                      // training row in octet
    const int p  = lane & 7;                       // 16B packet of 128B row
    const unsigned pOff = (unsigned)p * 16u;
    const char* embb = (const char*)emb8;

    unsigned short* xw = (unsigned short*)&xmem[wave][0];
    const int nchunks = (n + RPB - 1) / RPB;

    for (int chunk = blockIdx.x; chunk < nchunks; chunk += gridDim.x) {
        const int row0  = chunk * RPB;
        const int wrow0 = __builtin_amdgcn_readfirstlane(row0 + wave * 16);

        // ---- stage indices packed u16 (features 29..31 -> zero row 7424) --
        {
            const int4* xb = (const int4*)(x + (size_t)wrow0 * 32);
            int4 a = xb[lane * 2];
            int4 b = xb[lane * 2 + 1];
            if ((lane & 3) == 3) { b.y = 7424; b.z = 7424; b.w = 7424; }
            uint4 pk;
            pk.x = ((unsigned)a.x & 0xffffu) | ((unsigned)a.y << 16);
            pk.y = ((unsigned)a.z & 0xffffu) | ((unsigned)a.w << 16);
            pk.z = ((unsigned)b.x & 0xffffu) | ((unsigned)b.y << 16);
            pk.w = ((unsigned)b.z & 0xffffu) | ((unsigned)b.w << 16);
            ((uint4*)xw)[lane] = pk;
        }
        // same-wave DS ordering; no barriers in this phase.

        // ---- gather: 8 rows at once, serial 32-feature accumulate, NO shfl
        #pragma unroll 1
        for (int s = 0; s < 2; ++s) {
            const int r = s * 8 + rr;
            const unsigned short* xrow = xw + r * 32;
            unsigned aL0 = 0, aL1 = 0, aL2 = 0, aL3 = 0;
            unsigned aH0 = 0, aH1 = 0, aH2 = 0, aH3 = 0;
            #pragma unroll 8
            for (int j = 0; j < 32; ++j) {
                const unsigned idx = xrow[j];          // ds_read_u16 bcast
                const uint4 v = *(const uint4*)(embb + ((idx << 7) + pOff));
                aL0 += v.x & 0x00ff00ffu;
                aH0 += __builtin_amdgcn_perm(0u, v.x, 0x0c030c01u);
                aL1 += v.y & 0x00ff00ffu;
                aH1 += __builtin_amdgcn_perm(0u, v.y, 0x0c030c01u);
                aL2 += v.z & 0x00ff00ffu;
                aH2 += __builtin_amdgcn_perm(0u, v.z, 0x0c030c01u);
                aL3 += v.w & 0x00ff00ffu;
                aH3 += __builtin_amdgcn_perm(0u, v.w, 0x0c030c01u);
            }
            // dequant + bias removal + ReLU -> fp16 pairs (dims 16p..16p+15)
            uint4 U0, U1;
            {
                unsigned acc[8] = {aL0, aH0, aL1, aH1, aL2, aH2, aL3, aH3};
                unsigned uo[8];
                #pragma unroll
                for (int k = 0; k < 8; ++k) {
                    const unsigned w = acc[k];
                    float f0 = (float)(w & 0xffffu) * sc + cb;
                    float f1 = (float)(w >> 16)     * sc + cb;
                    h2v_t h;
                    h[0] = (_Float16)fmaxf(f0, 0.f);
                    h[1] = (_Float16)fmaxf(f1, 0.f);
                    uo[k] = __builtin_bit_cast(unsigned, h);
                }
                U0.x = uo[0]; U0.y = uo[1]; U0.z = uo[2]; U0.w = uo[3];
                U1.x = uo[4]; U1.y = uo[5]; U1.z = uo[6]; U1.w = uo[7];
            }
            // hT write: packet m at swizzled granule m ^ (r&7)
            char* hrow = &hmem[wave][r * 256];
            *(uint4*)(hrow + ((((2 * p)    ) ^ (r & 7)) << 4)) = U0;
            *(uint4*)(hrow + ((((2 * p) + 1) ^ (r & 7)) << 4)) = U1;
        }

        // ============ dense (per-wave MFMA, same wave's 16 rows) ===========
        const uint4* hT = (const uint4*)&hmem[wave][0];
        const int q  = lane >> 4;     // k-quad
        const int nn = lane & 15;     // A row m / B col n / C col n

        half8 bw2[2][4];
        #pragma unroll
        for (int nt = 0; nt < 2; ++nt)
            #pragma unroll
            for (int kk = 0; kk < 4; ++kk)
                bw2[nt][kk] = __builtin_bit_cast(half8,
                    *(const uint4*)((const char*)W2h +
                        ((nt * 16 + nn) * 128 + kk * 32 + q * 8) * 2));

        half8 af[4];
        #pragma unroll
        for (int kk = 0; kk < 4; ++kk)
            af[kk] = __builtin_bit_cast(half8,
                hT[nn * 16 + ((4 * kk + q) ^ (nn & 7))]);

        f32x4 acc0 = {0.f, 0.f, 0.f, 0.f}, acc1 = {0.f, 0.f, 0.f, 0.f};
        #pragma unroll
        for (int kk = 0; kk < 4; ++kk) {
            acc0 = __builtin_amdgcn_mfma_f32_16x16x32_f16(af[kk], bw2[0][kk], acc0, 0, 0, 0);
            acc1 = __builtin_amdgcn_mfma_f32_16x16x32_f16(af[kk], bw2[1][kk], acc1, 0, 0, 0);
        }
        const float bb0 = b2[nn], bb1 = b2[16 + nn];

        // CReLU + transpose via LDS (stride 68 halfs). a2 aliases hT:
        // all hT (af) reads completed above, same-wave program order.
        _Float16* a2 = (_Float16*)&hmem[wave][0];
        #pragma unroll
        for (int r = 0; r < 4; ++r) {
            const float v0 = acc0[r] + bb0;
            const float v1 = acc1[r] + bb1;
            const int m = q * 4 + r;
            a2[m * 68 + nn]      = (_Float16)fmaxf(v0, 0.f);
            a2[m * 68 + 16 + nn] = (_Float16)fmaxf(v1, 0.f);
            a2[m * 68 + 32 + nn] = (_Float16)fmaxf(-v0, 0.f);
            a2[m * 68 + 48 + nn] = (_Float16)fmaxf(-v1, 0.f);
        }

        half8 bw3[2][2];
        #pragma unroll
        for (int nt = 0; nt < 2; ++nt)
            #pragma unroll
            for (int kk = 0; kk < 2; ++kk)
                bw3[nt][kk] = __builtin_bit_cast(half8,
                    *(const uint4*)((const char*)W3h +
                        ((nt * 16 + nn) * 64 + kk * 32 + q * 8) * 2));

        half8 a2f[2];
        #pragma unroll
        for (int kk = 0; kk < 2; ++kk) {
            const _Float16* pp = &a2[nn * 68 + kk * 32 + q * 8];
            half8 t;
            #pragma unroll
            for (int j = 0; j < 8; ++j) t[j] = pp[j];
            a2f[kk] = t;
        }

        f32x4 acc30 = {0.f, 0.f, 0.f, 0.f}, acc31 = {0.f, 0.f, 0.f, 0.f};
        #pragma unroll
        for (int kk = 0; kk < 2; ++kk) {
            acc30 = __builtin_amdgcn_mfma_f32_16x16x32_f16(a2f[kk], bw3[0][kk], acc30, 0, 0, 0);
            acc31 = __builtin_amdgcn_mfma_f32_16x16x32_f16(a2f[kk], bw3[1][kk], acc31, 0, 0, 0);
        }
        const float bb30 = b3[nn], bb31 = b3[16 + nn];

        const float w4a = W4[nn],      w4b = W4[16 + nn];
        const float w4c = W4[32 + nn], w4d = W4[48 + nn];
        float o[4];
        #pragma unroll
        for (int r = 0; r < 4; ++r) {
            const float v0 = acc30[r] + bb30;
            const float v1 = acc31[r] + bb31;
            o[r] = fmaxf(v0, 0.f) * w4a + fmaxf(-v0, 0.f) * w4c
                 + fmaxf(v1, 0.f) * w4b + fmaxf(-v1, 0.f) * w4d;
        }
        #pragma unroll
        for (int s = 1; s < 16; s <<= 1) {
            #pragma unroll
            for (int r = 0; r < 4; ++r) o[r] += __shfl_xor(o[r], s);
        }
        if (nn == 0) {
            #pragma unroll
            for (int r = 0; r < 4; ++r) {
                const int row = wrow0 + q * 4 + r;
                if (row < n) out[row] = o[r];
            }
        }
    }
}

// ---------------- fallback (fp16 table + fp32-weight fused) ----------------
__global__ __launch_bounds__(256) void prep_fp16(
    const float* __restrict__ emb, __half2* __restrict__ emb16,
    int npairs_real, int npairs_tot)
{
    int i = blockIdx.x * blockDim.x + threadIdx.x;
    if (i < npairs_tot) {
        float2 v = make_float2(0.f, 0.f);
        if (i < npairs_real) v = ((const float2*)emb)[i];
        emb16[i] = __floats2half2_rn(v.x, v.y);
    }
}

__global__ __launch_bounds__(256) void nnue_fused(
    const int*    __restrict__ x,
    const __half* __restrict__ emb16,
    const float*  __restrict__ W2, const float* __restrict__ b2,
    const float*  __restrict__ W3, const float* __restrict__ b3,
    const float*  __restrict__ W4,
    float*        __restrict__ out, int n)
{
    __shared__ int     xlds[4][512];
    __shared__ __half2 hbuf[64][65];
    __shared__ float   h2T[32 * 64];
    __shared__ float   obuf[4][64];

    const int tid  = threadIdx.x;
    const int lane = tid & 63;
    const int wave = tid >> 6;
    const int row0 = blockIdx.x * RPB;
    const int wrow0 = __builtin_amdgcn_readfirstlane(row0 + wave * 16);
    const int g   = lane >> 4;
    const int sub = lane & 15;
    const unsigned subOff = (unsigned)sub * 16u;

    {
        const int4* xb = (const int4*)(x + (size_t)wrow0 * 32);
        int4 a = xb[lane * 2];
        int4 b = xb[lane * 2 + 1];
        if ((lane & 3) == 3) { b.y = 7424; b.z = 7424; b.w = 7424; }
        ((int4*)&xlds[wave][0])[lane * 2]     = a;
        ((int4*)&xlds[wave][0])[lane * 2 + 1] = b;
    }

    #pragma unroll 4
    for (int r = 0; r < 16; ++r) {
        const int* xrow = &xlds[wave][r * 32 + g];
        uint4 v[8];
        #pragma unroll
        for (int b = 0; b < 8; ++b) {
            const int idx = xrow[4 * b];
            const unsigned off = ((unsigned)idx << 8) + subOff;
            v[b] = *(const uint4*)((const char*)emb16 + off);
        }
        h2v_t hacc[4];
        #pragma unroll
        for (int q = 0; q < 4; ++q) hacc[q] = (h2v_t)0;
        #pragma unroll
        for (int b = 0; b < 8; ++b) {
            hacc[0] += __builtin_bit_cast(h2v_t, v[b].x);
            hacc[1] += __builtin_bit_cast(h2v_t, v[b].y);
            hacc[2] += __builtin_bit_cast(h2v_t, v[b].z);
            hacc[3] += __builtin_bit_cast(h2v_t, v[b].w);
        }
        #pragma unroll
        for (int q = 0; q < 4; ++q) {
            unsigned u = __builtin_bit_cast(unsigned, hacc[q]);
            h2v_t t = __builtin_bit_cast(h2v_t, u);
            t += __builtin_bit_cast(h2v_t, (unsigned)__shfl_xor((int)u, 16));
            unsigned u2 = __builtin_bit_cast(unsigned, t);
            t += __builtin_bit_cast(h2v_t, (unsigned)__shfl_xor((int)u2, 32));
            hacc[q] = __builtin_elementwise_max(t, (h2v_t)0);
        }
        if (g == 0) {
            const int row = wave * 16 + r;
            #pragma unroll
            for (int q = 0; q < 4; ++q)
                hbuf[row][sub * 4 + q] = __builtin_bit_cast(__half2, hacc[q]);
        }
    }
    __syncthreads();

    {
        const int j0 = wave * 8;
        const int rr = lane;
        float acc[8];
        #pragma unroll
        for (int j = 0; j < 8; ++j) acc[j] = b2[j0 + j];
        #pragma unroll
        for (int d2 = 0; d2 < 64; ++d2) {
            const __half2 hv = hbuf[rr][d2];
            const float vx = __low2float(hv), vy = __high2float(hv);
            #pragma unroll
            for (int j = 0; j < 8; ++j) {
                const float* w = W2 + (size_t)(j0 + j) * 128 + d2 * 2;
                acc[j] = fmaf(vx, w[0], acc[j]);
                acc[j] = fmaf(vy, w[1], acc[j]);
            }
        }
        #pragma unroll
        for (int j = 0; j < 8; ++j) h2T[(j0 + j) * 64 + rr] = acc[j];
    }
    __syncthreads();

    {
        const int j0 = wave * 8;
        const int rr = lane;
        float h2v[32];
        #pragma unroll
        for (int k = 0; k < 32; ++k) h2v[k] = h2T[k * 64 + rr];
        float acc[8];
        #pragma unroll
        for (int j = 0; j < 8; ++j) acc[j] = b3[j0 + j];
        #pragma unroll
        for (int k = 0; k < 32; ++k) {
            const float pz = fmaxf(h2v[k], 0.f);
            const float mz = fmaxf(-h2v[k], 0.f);
            #pragma unroll
            for (int j = 0; j < 8; ++j) {
                const float* w = W3 + (size_t)(j0 + j) * 64;
                acc[j] = fmaf(pz, w[k],      acc[j]);
                acc[j] = fmaf(mz, w[32 + k], acc[j]);
            }
        }
        float o = 0.f;
        #pragma unroll
        for (int j = 0; j < 8; ++j) {
            const int jj = j0 + j;
            o = fmaf(fmaxf(acc[j], 0.f),  W4[jj],      o);
            o = fmaf(fmaxf(-acc[j], 0.f), W4[32 + jj], o);
        }
        obuf[wave][rr] = o;
    }
    __syncthreads();

    if (tid < 64) {
        const int row = row0 + tid;
        if (row < n)
            out[row] = obuf[0][tid] + obuf[1][tid] + obuf[2][tid] + obuf[3][tid];
    }
}

extern "C" void kernel_launch(void* const* d_in, const int* in_sizes, int n_in,
                              void* d_out, int out_size, void* d_ws, size_t ws_size,
                              hipStream_t stream) {
    const int*   x   = (const int*)  d_in[0];
    const float* emb = (const float*)d_in[1];
    const float* W2  = (const float*)d_in[2];
    const float* b2  = (const float*)d_in[3];
    const float* W3  = (const float*)d_in[4];
    const float* b3  = (const float*)d_in[5];
    const float* W4  = (const float*)d_in[6];
    float* out = (float*)d_out;
    const int n = out_size;                 // 131072 rows

    // workspace layout (16B-aligned sections)
    const size_t emb8_bytes = (size_t)7425 * 128;           // 950,400
    const size_t w2h_off    = emb8_bytes;                   // +8192
    const size_t w3h_off    = w2h_off + 8192;               // +4096
    const size_t slots_off  = w3h_off + 4096;               // +4096 (1024 f32)
    const size_t need       = slots_off + 4096;

    if (ws_size >= need) {
        unsigned*     emb8  = (unsigned*)d_ws;
        _Float16*     W2h   = (_Float16*)((char*)d_ws + w2h_off);
        _Float16*     W3h   = (_Float16*)((char*)d_ws + w3h_off);
        float*        slots = (float*)((char*)d_ws + slots_off);
        const float4* emb4  = (const float4*)emb;

        const int n4 = 7424 * 32;   // 237,568 float4s; 1024x256 covers it
        hipLaunchKernelGGL(absmax_partial, dim3(1024), dim3(256), 0, stream,
                           emb4, slots, n4);

        static int nb_cached = 0;
        if (nb_cached == 0) {
            int bpc = 0;
            if (hipOccupancyMaxActiveBlocksPerMultiprocessor(
                    &bpc, nnue_all, 256, 0) != hipSuccess || bpc < 1)
                bpc = 1;
            int nb = bpc * 256;                 // 256 CUs on MI355X
            if (nb > 1024) nb = 1024;
            nb_cached = nb;
        }

        int n_arg = n;
        void* args[] = {(void*)&x, (void*)&emb4, (void*)&emb8,
                        (void*)&W2, (void*)&W3, (void*)&W2h, (void*)&W3h,
                        (void*)&b2, (void*)&b3, (void*)&W4,
                        (void*)&slots, (void*)&out, (void*)&n_arg};
        hipLaunchCooperativeKernel((void*)nnue_all, dim3(nb_cached), dim3(256),
                                   args, 0, stream);
    } else {
        // legacy fallback: fp16 table + fp32-weight fused kernel
        __half2* emb16 = (__half2*)d_ws;
        const int npairs_real = 7424 * 64;
        const int npairs_tot  = 7425 * 64;
        hipLaunchKernelGGL(prep_fp16, dim3((npairs_tot + 255) / 256), dim3(256),
                           0, stream, emb, emb16, npairs_real, npairs_tot);
        hipLaunchKernelGGL(nnue_fused, dim3((n + RPB - 1) / RPB), dim3(256),
                           0, stream, x, (const __half*)emb16, W2, b2, W3, b3,
                           W4, out, n);
    }
}